// Round 6
// baseline (19244.455 us; speedup 1.0000x reference)
//
#include <hip/hip_runtime.h>
#include <math.h>

// Problem constants
#define B_    32
#define T_    1000
#define E_    512
#define D_    1024
#define A_    512
#define C_    10
#define F_    100
#define ODIM_ 5000
#define OLEN_ 101
#define SOS_  4998

// ---- workspace layout (float offsets) ---- total ~20.2M floats = 80.7 MB
#define OFF_PRE   0u                        // bf16 PRE_T [B][A][T] (ushort)
#define N_PREF    (32u*512u*1000u/2u)       // 8,192,000 floats
#define OFF_HPB   (OFF_PRE + N_PREF)        // bf16 hpad [B][T][E] (ushort)
#define N_HPBF    (32u*1000u*512u/2u)       // 8,192,000 floats
#define OFF_DEC   (OFF_HPB + N_HPBF)        // [B][A]
#define N_DEC     (32u*512u)
#define OFF_CONV  (OFF_DEC + N_DEC)         // [B][C][T] fp32 (normalized by prev S)
#define N_CONVB   (32u*10u*1000u)
#define OFF_AW    (OFF_CONV + N_CONVB)      // [B][T] UNNORMALIZED w~ = exp(2e)
#define N_AW      (32u*1000u)
#define OFF_S     (OFF_AW + N_AW)           // [2][32] softmax denominators (dbuf by parity)
#define N_S       (64u)
#define OFF_CTX   (OFF_S + N_S)             // [B][E] UNNORMALIZED ctx
#define N_CTX     (32u*512u)
#define OFF_Z     (OFF_CTX + N_CTX)         // [2][B][D] z double-buffer (step parity)
#define N_Z1      (32u*1024u)
#define OFF_C     (OFF_Z + 2u*N_Z1)         // [B][D]
#define OFF_ZALL  (OFF_C + N_Z1)            // [101][B][D]

// ---- fast transcendentals ----
__device__ __forceinline__ float fast_tanh(float x) {
    float cx = fminf(8.f, fmaxf(-8.f, x));
    float e = __expf(2.f * cx);
    return (e - 1.f) * __builtin_amdgcn_rcpf(e + 1.f);
}
__device__ __forceinline__ float fast_sigmoid(float x) {
    float cx = fminf(30.f, fmaxf(-30.f, x));
    return __builtin_amdgcn_rcpf(1.f + __expf(-cx));
}

// ---- bf16 pack (round-to-nearest-even) / unpack ----
__device__ __forceinline__ unsigned bf16rne(float f) {
    unsigned u = __float_as_uint(f);
    return (u + 0x7fffu + ((u >> 16) & 1u)) >> 16;
}
__device__ __forceinline__ unsigned packbf(float lo, float hi) {
    return bf16rne(lo) | (bf16rne(hi) << 16);
}
__device__ __forceinline__ float bflo(unsigned u) { return __uint_as_float(u << 16); }
__device__ __forceinline__ float bfhi(unsigned u) { return __uint_as_float(u & 0xffff0000u); }

// ---------------- init: z0=0, c=0, ctx=0, w~=1, S[1]=1000 ----------------
__global__ __launch_bounds__(256) void k_init(float* ws) {
    int i = blockIdx.x * 256 + threadIdx.x;
    if (i < (int)N_Z1) { ws[OFF_Z + i] = 0.f; ws[OFF_C + i] = 0.f; }
    if (i < (int)N_CTX) ws[OFF_CTX + i] = 0.f;
    if (i < (int)N_AW) ws[OFF_AW + i] = 1.0f;       // uniform: w~=1, S=1000
    if (i < 64) ws[OFF_S + i] = (i >= 32) ? 1000.f : 0.f;
}

// ---------------- hpad -> bf16 copy (once) ----------------
__global__ __launch_bounds__(256) void k_hp16(const float* __restrict__ hp, float* ws) {
    uint2* hpb = (uint2*)(ws + OFF_HPB);
    const float4* src = (const float4*)hp;
    for (unsigned i = blockIdx.x * 256 + threadIdx.x; i < 4096000u; i += 4000u * 256u) {
        float4 v = src[i];
        uint2 o;
        o.x = packbf(v.x, v.y);
        o.y = packbf(v.z, v.w);
        hpb[i] = o;
    }
}

// ---------------- pre_t[b][a][t] = (hpad @ w_enc^T + b_enc), bf16, transposed (once) ----------------
__global__ __launch_bounds__(256) void k_pre_t(const float* __restrict__ hp,
                                               const float* __restrict__ we,
                                               const float* __restrict__ be,
                                               float* ws) {
    __shared__ float As[64][68];
    __shared__ float Bs[64][68];
    unsigned short* preb = (unsigned short*)(ws + OFF_PRE);
    int bt = blockIdx.y;
    int b = bt >> 4, tc = bt & 15;
    int t0 = tc * 64;
    int n0 = blockIdx.x * 64;
    int tid = threadIdx.x;
    int tr = tid >> 4, tcl = tid & 15;
    float acc[4][4] = {};
    for (int k0 = 0; k0 < 512; k0 += 64) {
        for (int i = tid; i < 1024; i += 256) {
            int m = i >> 4, kq = (i & 15) << 2;
            int t = t0 + m;
            float4 v = (t < 1000) ? *(const float4*)&hp[((size_t)(b * 1000 + t)) * 512 + k0 + kq]
                                  : make_float4(0.f, 0.f, 0.f, 0.f);
            As[kq + 0][m] = v.x; As[kq + 1][m] = v.y; As[kq + 2][m] = v.z; As[kq + 3][m] = v.w;
            float4 w = *(const float4*)&we[(size_t)(n0 + m) * 512 + k0 + kq];
            Bs[kq + 0][m] = w.x; Bs[kq + 1][m] = w.y; Bs[kq + 2][m] = w.z; Bs[kq + 3][m] = w.w;
        }
        __syncthreads();
        #pragma unroll 16
        for (int kk = 0; kk < 64; ++kk) {
            float4 av = *(const float4*)&As[kk][tr << 2];
            float4 bv = *(const float4*)&Bs[kk][tcl << 2];
            float a[4] = {av.x, av.y, av.z, av.w};
            float bq[4] = {bv.x, bv.y, bv.z, bv.w};
            #pragma unroll
            for (int i = 0; i < 4; i++)
                #pragma unroll
                for (int j = 0; j < 4; j++) acc[i][j] += a[i] * bq[j];
        }
        __syncthreads();
    }
    int tt = t0 + (tr << 2);
    if (tt < 1000) {
        #pragma unroll
        for (int j = 0; j < 4; ++j) {
            int a = n0 + (tcl << 2) + j;
            float bea = be[a];
            uint2 o;
            o.x = packbf(acc[0][j] + bea, acc[1][j] + bea);
            o.y = packbf(acc[2][j] + bea, acc[3][j] + bea);
            *(uint2*)&preb[((size_t)(b * 512 + a)) * 1000 + tt] = o;
        }
    }
}

// ---------------- K1: dec + conv(normalized) only ----------------
// blocks [0,1024): dec (+ ctx/S zero duties). [1024,1344): conv.
__global__ __launch_bounds__(256, 2) void k_prep(const float* __restrict__ wdec,
                                                 const float* __restrict__ wconv,
                                                 float* ws, int step) {
    int tid = threadIdx.x;
    if (blockIdx.x < 1024) {
        int u = blockIdx.x;
        if (u < 64) ws[OFF_CTX + u * 256 + tid] = 0.f;
        if (u == 64 && tid < 32) ws[OFF_S + (step & 1) * 32 + tid] = 0.f;
        int w = u * 4 + (tid >> 6);      // 0..4095
        int lane = tid & 63;
        int a = w >> 3, bg7 = w & 7;
        const float* zin = ws + OFF_Z + (step & 1) * N_Z1;
        const float4* wr = (const float4*)(wdec + (size_t)a * 1024);
        float4 w4[4];
        #pragma unroll
        for (int i = 0; i < 4; i++) w4[i] = wr[i * 64 + lane];
        float acc[4] = {0.f, 0.f, 0.f, 0.f};
        #pragma unroll
        for (int bb = 0; bb < 4; ++bb) {
            const float4* zr = (const float4*)(zin + (size_t)(bg7 * 4 + bb) * 1024);
            #pragma unroll
            for (int i = 0; i < 4; i++) {
                float4 z4 = zr[i * 64 + lane];
                acc[bb] += w4[i].x * z4.x + w4[i].y * z4.y + w4[i].z * z4.z + w4[i].w * z4.w;
            }
        }
        #pragma unroll
        for (int off = 32; off > 0; off >>= 1) {
            acc[0] += __shfl_xor(acc[0], off, 64);
            acc[1] += __shfl_xor(acc[1], off, 64);
            acc[2] += __shfl_xor(acc[2], off, 64);
            acc[3] += __shfl_xor(acc[3], off, 64);
        }
        if (lane == 0) {
            #pragma unroll
            for (int bb = 0; bb < 4; ++bb)
                ws[OFF_DEC + (bg7 * 4 + bb) * 512 + a] = acc[bb];
        }
    } else {
        int blk = blockIdx.x - 1024;   // 0..319
        int b = blk / 10, c = blk - b * 10;
        if (tid >= 250) return;
        float invS = __builtin_amdgcn_rcpf(ws[OFF_S + ((step + 1) & 1) * 32 + b]);
        int t = tid * 4;
        const float* ar = ws + OFF_AW + b * 1000;
        const float* wc = wconv + c * 201;
        float a0, a1, a2, a3;
        a0 = (t - 100 >= 0) ? ar[t - 100] : 0.f;
        a1 = (t -  99 >= 0) ? ar[t -  99] : 0.f;
        a2 = (t -  98 >= 0) ? ar[t -  98] : 0.f;
        a3 = (t -  97 >= 0) ? ar[t -  97] : 0.f;
        float c0 = 0.f, c1 = 0.f, c2 = 0.f, c3 = 0.f;
        #pragma unroll 4
        for (int j = 0; j < 201; ++j) {
            float w = wc[j];
            c0 += a0 * w; c1 += a1 * w; c2 += a2 * w; c3 += a3 * w;
            a0 = a1; a1 = a2; a2 = a3;
            int ni = t + j - 96;
            a3 = (ni >= 0 && ni < 1000) ? ar[ni] : 0.f;
        }
        float* o = ws + OFF_CONV + (size_t)(b * 10 + c) * 1000 + t;
        o[0] = c0 * invS; o[1] = c1 * invS; o[2] = c2 * invS; o[3] = c3 * invS;
    }
}

// ---------------- K2: fused energy + w~=exp(2e) + S + ctx (bf16 streams, LDS params) ----------------
__global__ __launch_bounds__(512, 2) void k_ectx(const float* __restrict__ watt,
                                                 const float* __restrict__ gvec,
                                                 const float* __restrict__ bgv,
                                                 float* ws, int step) {
    __shared__ float sa[512 * 12];   // 24 KB: per-a record {watt[10], gvec, dec}
    __shared__ float part[1024];
    __shared__ float wsh[128];
    const unsigned short* preb = (const unsigned short*)(ws + OFF_PRE);
    const unsigned short* hpb  = (const unsigned short*)(ws + OFF_HPB);
    int b = blockIdx.x >> 3, tc = blockIdx.x & 7;
    int tbase = tc * 128;
    int tid = threadIdx.x;
    {
        const float* wrow = watt + tid * 10;
        float* d = sa + tid * 12;
        #pragma unroll
        for (int c = 0; c < 10; ++c) d[c] = wrow[c];
        d[10] = gvec[tid];
        d[11] = ws[OFF_DEC + b * 512 + tid];
    }
    __syncthreads();
    int w = tid >> 6, l = tid & 63;
    int t = tbase + l * 2;
    bool valid = (t < 1000);
    float2 cvv[10];
    const float* convb = ws + OFF_CONV + b * 10000;
    #pragma unroll
    for (int c = 0; c < 10; ++c)
        cvv[c] = valid ? *(const float2*)&convb[c * 1000 + t] : make_float2(0.f, 0.f);
    int a0 = w * 64;
    const unsigned short* pt = preb + ((size_t)(b * 512 + a0)) * 1000 + t;
    float ex = 0.f, ey = 0.f;
    #pragma unroll 8
    for (int a = a0; a < a0 + 64; ++a) {
        unsigned u = valid ? *(const unsigned*)pt : 0u;
        pt += 1000;
        const float4* sp = (const float4*)(sa + a * 12);
        float4 w0 = sp[0];
        float4 w1 = sp[1];
        float4 w2 = sp[2];   // {watt8, watt9, gvec, dec}
        float px = bflo(u), py = bfhi(u);
        float sx = px + w2.w, sy = py + w2.w;
        sx += cvv[0].x * w0.x; sy += cvv[0].y * w0.x;
        sx += cvv[1].x * w0.y; sy += cvv[1].y * w0.y;
        sx += cvv[2].x * w0.z; sy += cvv[2].y * w0.z;
        sx += cvv[3].x * w0.w; sy += cvv[3].y * w0.w;
        sx += cvv[4].x * w1.x; sy += cvv[4].y * w1.x;
        sx += cvv[5].x * w1.y; sy += cvv[5].y * w1.y;
        sx += cvv[6].x * w1.z; sy += cvv[6].y * w1.z;
        sx += cvv[7].x * w1.w; sy += cvv[7].y * w1.w;
        sx += cvv[8].x * w2.x; sy += cvv[8].y * w2.x;
        sx += cvv[9].x * w2.y; sy += cvv[9].y * w2.y;
        ex += w2.z * fast_tanh(sx);
        ey += w2.z * fast_tanh(sy);
    }
    part[w * 128 + l * 2]     = ex;
    part[w * 128 + l * 2 + 1] = ey;
    __syncthreads();
    float wtil = 0.f;
    if (tid < 128) {
        int tt = tbase + tid;
        float e = 0.f;
        #pragma unroll
        for (int j = 0; j < 8; ++j) e += part[j * 128 + tid];
        if (tt < 1000) {
            wtil = __expf(2.f * (e + bgv[0]));   // |2(e+bg)| <= ~17: no max-sub needed
            ws[OFF_AW + b * 1000 + tt] = wtil;
        }
        wsh[tid] = wtil;
    }
    __syncthreads();
    // S: 2 wave shuffle-reduces instead of 9-barrier tree
    if (tid < 128) {
        float ss = wtil;
        #pragma unroll
        for (int off = 32; off > 0; off >>= 1) ss += __shfl_xor(ss, off, 64);
        if ((tid & 63) == 0) part[tid >> 6] = ss;
    }
    __syncthreads();
    if (tid == 0) atomicAdd(&ws[OFF_S + (step & 1) * 32 + b], part[0] + part[1]);
    // ctx accumulate for this t-chunk (bf16 hpad)
    int e4 = tid & 127, th = tid >> 7;
    int lt0 = th * 32;
    int ltend = lt0 + 32;
    int tmax = 1000 - tbase; if (ltend > tmax) ltend = tmax;
    float4 acc = make_float4(0.f, 0.f, 0.f, 0.f);
    for (int lt = lt0; lt < ltend; ++lt) {
        float wv = wsh[lt];
        uint2 hu = *(const uint2*)&hpb[((size_t)(b * 1000 + tbase + lt)) * 512 + e4 * 4];
        acc.x += wv * bflo(hu.x); acc.y += wv * bfhi(hu.x);
        acc.z += wv * bflo(hu.y); acc.w += wv * bfhi(hu.y);
    }
    float* cx = ws + OFF_CTX + b * 512 + e4 * 4;
    atomicAdd(cx + 0, acc.x); atomicAdd(cx + 1, acc.y);
    atomicAdd(cx + 2, acc.z); atomicAdd(cx + 3, acc.w);
}

// ---------------- K3: FULL-K gates GEMM (K=2560: ey|ctx/S|z) + LSTM ----------------
// 256 blocks x 256 threads. Block owns 4 d's -> 16 gate rows. z double-buffered.
__global__ __launch_bounds__(256, 2) void k_gl(const float* __restrict__ wih,
                                               const float* __restrict__ whh,
                                               const float* __restrict__ embed,
                                               const int* __restrict__ ys,
                                               const float* __restrict__ bih,
                                               const float* __restrict__ bhh,
                                               float* ws, int step) {
    __shared__ float wlds[64][17];
    __shared__ float xs[64][33];
    __shared__ float glb[16][33];
    __shared__ float sinv[32];
    __shared__ int   toks[32];
    int tid = threadIdx.x;
    int d0 = blockIdx.x * 4;
    if (tid < 32) {
        sinv[tid] = __builtin_amdgcn_rcpf(ws[OFF_S + (step & 1) * 32 + tid]);
        toks[tid] = (step == 0) ? SOS_ : ys[tid * 100 + step - 1];
    }
    __syncthreads();
    int r = tid >> 4, kq4 = (tid & 15) * 4;          // W staging: 16 rows x 64 k
    int ng_r = (r >> 2) * 1024 + d0 + (r & 3);
    int bx = tid >> 3, kq8 = (tid & 7) * 8;          // x staging: 32 b x 64 k
    float xscale = sinv[bx];
    int tok = toks[bx];
    const float* zin = ws + OFF_Z + (step & 1) * N_Z1;
    int nq = tid & 7, bq = tid >> 3;                 // compute: 8 row-pairs x 32 b
    float acc0 = 0.f, acc1 = 0.f;
    for (int kc = 0; kc < 40; ++kc) {
        int k0 = kc * 64;
        {   // stage W (chunks never straddle the 1536 boundary: 1536/64=24)
            const float* wsrc = (k0 < 1536)
                ? (wih + (size_t)ng_r * 1536 + k0 + kq4)
                : (whh + (size_t)ng_r * 1024 + (k0 - 1536) + kq4);
            float4 wv = *(const float4*)wsrc;
            wlds[kq4 + 0][r] = wv.x; wlds[kq4 + 1][r] = wv.y;
            wlds[kq4 + 2][r] = wv.z; wlds[kq4 + 3][r] = wv.w;
        }
        {   // stage x (chunks pure: ey k<1024, ctx 1024..1536, z >=1536)
            float4 v0, v1;
            float sc = 1.f;
            if (k0 < 1024) {
                const float* s = embed + (size_t)tok * 1024 + k0 + kq8;
                v0 = ((const float4*)s)[0]; v1 = ((const float4*)s)[1];
            } else if (k0 < 1536) {
                const float* s = ws + OFF_CTX + (size_t)bx * 512 + (k0 - 1024) + kq8;
                v0 = ((const float4*)s)[0]; v1 = ((const float4*)s)[1];
                sc = xscale;
            } else {
                const float* s = zin + (size_t)bx * 1024 + (k0 - 1536) + kq8;
                v0 = ((const float4*)s)[0]; v1 = ((const float4*)s)[1];
            }
            xs[kq8 + 0][bx] = v0.x * sc; xs[kq8 + 1][bx] = v0.y * sc;
            xs[kq8 + 2][bx] = v0.z * sc; xs[kq8 + 3][bx] = v0.w * sc;
            xs[kq8 + 4][bx] = v1.x * sc; xs[kq8 + 5][bx] = v1.y * sc;
            xs[kq8 + 6][bx] = v1.z * sc; xs[kq8 + 7][bx] = v1.w * sc;
        }
        __syncthreads();
        #pragma unroll 16
        for (int kk = 0; kk < 64; ++kk) {
            float w0 = wlds[kk][nq * 2], w1 = wlds[kk][nq * 2 + 1];
            float x  = xs[kk][bq];
            acc0 += w0 * x;
            acc1 += w1 * x;
        }
        __syncthreads();
    }
    {
        int nl0 = nq * 2, nl1 = nq * 2 + 1;
        int ng0 = (nl0 >> 2) * 1024 + d0 + (nl0 & 3);
        int ng1 = (nl1 >> 2) * 1024 + d0 + (nl1 & 3);
        glb[nl0][bq] = acc0 + bih[ng0] + bhh[ng0];
        glb[nl1][bq] = acc1 + bih[ng1] + bhh[ng1];
    }
    __syncthreads();
    if (tid < 128) {
        int dl = tid >> 5, b = tid & 31;
        float gi = glb[dl][b];
        float gf = glb[4 + dl][b];
        float gg = glb[8 + dl][b];
        float go = glb[12 + dl][b];
        int idl = b * 1024 + d0 + dl;
        float c_old = ws[OFF_C + idl];
        float si = fast_sigmoid(gi);
        float sf = fast_sigmoid(gf);
        float so = fast_sigmoid(go);
        float cn = sf * c_old + si * fast_tanh(gg);
        float hh = so * fast_tanh(cn);
        ws[OFF_C + idl] = cn;
        ws[OFF_Z + ((step + 1) & 1) * N_Z1 + idl] = hh;
        ws[OFF_ZALL + ((size_t)step * 32 + b) * 1024 + d0 + dl] = hh;
    }
}

// ---------------- final: out = zall @ w_out^T + b_out (128x128 tile, 8x8/thread) ----------------
__global__ __launch_bounds__(256) void k_out(const float* __restrict__ zall,
                                             const float* __restrict__ wo,
                                             const float* __restrict__ bo,
                                             float* __restrict__ out) {
    __shared__ float As[16][132];
    __shared__ float Bs[16][132];
    int m0 = blockIdx.y * 128, n0 = blockIdx.x * 128;
    int tid = threadIdx.x;
    int tx = tid & 15, ty = tid >> 4;
    float acc[8][8] = {};
    int ar = tid >> 1, ah = (tid & 1) * 8;
    for (int k0 = 0; k0 < 1024; k0 += 16) {
        {
            int gm = m0 + ar;
            float4 a0, a1;
            if (gm < 3232) {
                a0 = *(const float4*)&zall[(size_t)gm * 1024 + k0 + ah];
                a1 = *(const float4*)&zall[(size_t)gm * 1024 + k0 + ah + 4];
            } else { a0 = a1 = make_float4(0.f, 0.f, 0.f, 0.f); }
            As[ah + 0][ar] = a0.x; As[ah + 1][ar] = a0.y; As[ah + 2][ar] = a0.z; As[ah + 3][ar] = a0.w;
            As[ah + 4][ar] = a1.x; As[ah + 5][ar] = a1.y; As[ah + 6][ar] = a1.z; As[ah + 7][ar] = a1.w;
            int gn = n0 + ar;
            float4 b0, b1;
            if (gn < 5000) {
                b0 = *(const float4*)&wo[(size_t)gn * 1024 + k0 + ah];
                b1 = *(const float4*)&wo[(size_t)gn * 1024 + k0 + ah + 4];
            } else { b0 = b1 = make_float4(0.f, 0.f, 0.f, 0.f); }
            Bs[ah + 0][ar] = b0.x; Bs[ah + 1][ar] = b0.y; Bs[ah + 2][ar] = b0.z; Bs[ah + 3][ar] = b0.w;
            Bs[ah + 4][ar] = b1.x; Bs[ah + 5][ar] = b1.y; Bs[ah + 6][ar] = b1.z; Bs[ah + 7][ar] = b1.w;
        }
        __syncthreads();
        #pragma unroll
        for (int kk = 0; kk < 16; ++kk) {
            float4 a0v = *(const float4*)&As[kk][ty * 8];
            float4 a1v = *(const float4*)&As[kk][ty * 8 + 4];
            float4 b0v = *(const float4*)&Bs[kk][tx * 8];
            float4 b1v = *(const float4*)&Bs[kk][tx * 8 + 4];
            float am[8] = {a0v.x, a0v.y, a0v.z, a0v.w, a1v.x, a1v.y, a1v.z, a1v.w};
            float bn[8] = {b0v.x, b0v.y, b0v.z, b0v.w, b1v.x, b1v.y, b1v.z, b1v.w};
            #pragma unroll
            for (int i = 0; i < 8; i++)
                #pragma unroll
                for (int j = 0; j < 8; j++) acc[i][j] += am[i] * bn[j];
        }
        __syncthreads();
    }
    #pragma unroll
    for (int i = 0; i < 8; i++) {
        int m = m0 + ty * 8 + i;
        if (m >= 3232) continue;
        int b = m & 31, o = m >> 5;
        #pragma unroll
        for (int j = 0; j < 8; j++) {
            int v = n0 + tx * 8 + j;
            if (v < 5000)
                out[((size_t)b * 101 + o) * 5000 + v] = acc[i][j] + bo[v];
        }
    }
}

extern "C" void kernel_launch(void* const* d_in, const int* in_sizes, int n_in,
                              void* d_out, int out_size, void* d_ws, size_t ws_size,
                              hipStream_t stream) {
    const float* hpad   = (const float*)d_in[0];
    const int*   ys     = (const int*)d_in[1];
    const float* w_enc  = (const float*)d_in[2];
    const float* b_enc  = (const float*)d_in[3];
    const float* w_dec  = (const float*)d_in[4];
    const float* w_att  = (const float*)d_in[5];
    const float* w_conv = (const float*)d_in[6];
    const float* w_gvec = (const float*)d_in[7];
    const float* b_gvec = (const float*)d_in[8];
    const float* embed  = (const float*)d_in[9];
    const float* w_ih   = (const float*)d_in[10];
    const float* w_hh   = (const float*)d_in[11];
    const float* b_ih   = (const float*)d_in[12];
    const float* b_hh   = (const float*)d_in[13];
    const float* w_out  = (const float*)d_in[14];
    const float* b_out  = (const float*)d_in[15];
    float* ws  = (float*)d_ws;
    float* out = (float*)d_out;

    k_init<<<128, 256, 0, stream>>>(ws);
    k_hp16<<<4000, 256, 0, stream>>>(hpad, ws);
    k_pre_t<<<dim3(8, 512), 256, 0, stream>>>(hpad, w_enc, b_enc, ws);

    for (int step = 0; step < OLEN_; ++step) {
        k_prep<<<1344, 256, 0, stream>>>(w_dec, w_conv, ws, step);
        k_ectx<<<256, 512, 0, stream>>>(w_att, w_gvec, b_gvec, ws, step);
        k_gl<<<256, 256, 0, stream>>>(w_ih, w_hh, embed, ys, b_ih, b_hh, ws, step);
    }

    k_out<<<dim3(40, 26), 256, 0, stream>>>(ws + OFF_ZALL, w_out, b_out, out);
}

// Round 7
// 9958.145 us; speedup vs baseline: 1.9325x; 1.9325x over previous
//
#include <hip/hip_runtime.h>
#include <math.h>

// Problem constants
#define B_    32
#define T_    1000
#define E_    512
#define D_    1024
#define A_    512
#define C_    10
#define F_    100
#define ODIM_ 5000
#define OLEN_ 101
#define SOS_  4998

// ---- workspace layout (float offsets) ----
#define OFF_PRE   0u                        // bf16 PRE_T [B][A][T] (ushort)
#define N_PREF    (32u*512u*1000u/2u)       // 8,192,000 floats
#define OFF_HPB   (OFF_PRE + N_PREF)        // bf16 hpad [B][T][E] (ushort)
#define N_HPBF    (32u*1000u*512u/2u)       // 8,192,000 floats
#define OFF_PP    (OFF_HPB + N_HPBF)        // [B][A][12] param recs {watt[10],gvec,dec}
#define N_PP      (32u*512u*12u)            // 196,608
#define OFF_CONV  (OFF_PP + N_PP)           // [B][C][T] fp32 (normalized by prev S)
#define N_CONVB   (32u*10u*1000u)
#define OFF_AW    (OFF_CONV + N_CONVB)      // [B][T] UNNORMALIZED w~ = exp(2e)
#define N_AW      (32u*1000u)
#define OFF_S     (OFF_AW + N_AW)           // [2][32] softmax denominators (dbuf by parity)
#define N_S       (64u)
#define OFF_CTX   (OFF_S + N_S)             // [B][E] UNNORMALIZED ctx
#define N_CTX     (32u*512u)
#define OFF_GP    (OFF_CTX + N_CTX)         // 8 slots x [B][4096] ey/z gate partials
#define N_GP      (8u*32u*4096u)
#define OFF_Z     (OFF_GP + N_GP)           // [B][D]
#define N_Z1      (32u*1024u)
#define OFF_C     (OFF_Z + N_Z1)            // [B][D]
#define OFF_ZALL  (OFF_C + N_Z1)            // [101][B][D]

// ---- fast transcendentals ----
__device__ __forceinline__ float fast_tanh(float x) {
    float cx = fminf(8.f, fmaxf(-8.f, x));
    float e = __expf(2.f * cx);
    return (e - 1.f) * __builtin_amdgcn_rcpf(e + 1.f);
}
__device__ __forceinline__ float fast_sigmoid(float x) {
    float cx = fminf(30.f, fmaxf(-30.f, x));
    return __builtin_amdgcn_rcpf(1.f + __expf(-cx));
}

// ---- bf16 pack (round-to-nearest-even) / unpack ----
__device__ __forceinline__ unsigned bf16rne(float f) {
    unsigned u = __float_as_uint(f);
    return (u + 0x7fffu + ((u >> 16) & 1u)) >> 16;
}
__device__ __forceinline__ unsigned packbf(float lo, float hi) {
    return bf16rne(lo) | (bf16rne(hi) << 16);
}
__device__ __forceinline__ float bflo(unsigned u) { return __uint_as_float(u << 16); }
__device__ __forceinline__ float bfhi(unsigned u) { return __uint_as_float(u & 0xffff0000u); }

// ---------------- init: z=0, c=0, ctx=0, w~=1, S[1]=1000, pp watt/gvec fill ----------------
__global__ __launch_bounds__(256) void k_init(const float* __restrict__ watt,
                                              const float* __restrict__ gvec,
                                              float* ws) {
    int i = blockIdx.x * 256 + threadIdx.x;
    if (i < (int)N_Z1) { ws[OFF_Z + i] = 0.f; ws[OFF_C + i] = 0.f; }
    if (i < (int)N_CTX) ws[OFF_CTX + i] = 0.f;
    if (i < (int)N_AW) ws[OFF_AW + i] = 1.0f;       // uniform: w~=1, S=1000
    if (i < 64) ws[OFF_S + i] = (i >= 32) ? 1000.f : 0.f;
    if (i < 16384) {                                 // (b,a) param records
        int a = i & 511;
        float* d = ws + OFF_PP + (size_t)i * 12;
        #pragma unroll
        for (int c = 0; c < 10; ++c) d[c] = watt[a * 10 + c];
        d[10] = gvec[a];
        // d[11] (dec) written each step by k_prep
    }
}

// ---------------- hpad -> bf16 copy (once) ----------------
__global__ __launch_bounds__(256) void k_hp16(const float* __restrict__ hp, float* ws) {
    uint2* hpb = (uint2*)(ws + OFF_HPB);
    const float4* src = (const float4*)hp;
    for (unsigned i = blockIdx.x * 256 + threadIdx.x; i < 4096000u; i += 4000u * 256u) {
        float4 v = src[i];
        uint2 o;
        o.x = packbf(v.x, v.y);
        o.y = packbf(v.z, v.w);
        hpb[i] = o;
    }
}

// ---------------- pre_t[b][a][t] = (hpad @ w_enc^T + b_enc), bf16, transposed (once) ----------------
__global__ __launch_bounds__(256) void k_pre_t(const float* __restrict__ hp,
                                               const float* __restrict__ we,
                                               const float* __restrict__ be,
                                               float* ws) {
    __shared__ float As[64][68];
    __shared__ float Bs[64][68];
    unsigned short* preb = (unsigned short*)(ws + OFF_PRE);
    int bt = blockIdx.y;
    int b = bt >> 4, tc = bt & 15;
    int t0 = tc * 64;
    int n0 = blockIdx.x * 64;
    int tid = threadIdx.x;
    int tr = tid >> 4, tcl = tid & 15;
    float acc[4][4] = {};
    for (int k0 = 0; k0 < 512; k0 += 64) {
        for (int i = tid; i < 1024; i += 256) {
            int m = i >> 4, kq = (i & 15) << 2;
            int t = t0 + m;
            float4 v = (t < 1000) ? *(const float4*)&hp[((size_t)(b * 1000 + t)) * 512 + k0 + kq]
                                  : make_float4(0.f, 0.f, 0.f, 0.f);
            As[kq + 0][m] = v.x; As[kq + 1][m] = v.y; As[kq + 2][m] = v.z; As[kq + 3][m] = v.w;
            float4 w = *(const float4*)&we[(size_t)(n0 + m) * 512 + k0 + kq];
            Bs[kq + 0][m] = w.x; Bs[kq + 1][m] = w.y; Bs[kq + 2][m] = w.z; Bs[kq + 3][m] = w.w;
        }
        __syncthreads();
        #pragma unroll 16
        for (int kk = 0; kk < 64; ++kk) {
            float4 av = *(const float4*)&As[kk][tr << 2];
            float4 bv = *(const float4*)&Bs[kk][tcl << 2];
            float a[4] = {av.x, av.y, av.z, av.w};
            float bq[4] = {bv.x, bv.y, bv.z, bv.w};
            #pragma unroll
            for (int i = 0; i < 4; i++)
                #pragma unroll
                for (int j = 0; j < 4; j++) acc[i][j] += a[i] * bq[j];
        }
        __syncthreads();
    }
    int tt = t0 + (tr << 2);
    if (tt < 1000) {
        #pragma unroll
        for (int j = 0; j < 4; ++j) {
            int a = n0 + (tcl << 2) + j;
            float bea = be[a];
            uint2 o;
            o.x = packbf(acc[0][j] + bea, acc[1][j] + bea);
            o.y = packbf(acc[2][j] + bea, acc[3][j] + bea);
            *(uint2*)&preb[((size_t)(b * 512 + a)) * 1000 + tt] = o;
        }
    }
}

// ---------------- K1: dec + conv(normalized) + ey/z gate partials ----------------
__global__ __launch_bounds__(256, 2) void k_prep(const float* __restrict__ wdec,
                                                 const float* __restrict__ wconv,
                                                 const float* __restrict__ wih,
                                                 const float* __restrict__ whh,
                                                 const float* __restrict__ embed,
                                                 const int* __restrict__ ys,
                                                 float* ws, int step) {
    int tid = threadIdx.x;
    if (blockIdx.x < 1024) {
        int u = blockIdx.x;
        if (u < 64) ws[OFF_CTX + u * 256 + tid] = 0.f;
        if (u == 64 && tid < 32) ws[OFF_S + (step & 1) * 32 + tid] = 0.f;
        int w = u * 4 + (tid >> 6);      // 0..4095
        int lane = tid & 63;
        int a = w >> 3, bg7 = w & 7;
        const float4* wr = (const float4*)(wdec + (size_t)a * 1024);
        float4 w4[4];
        #pragma unroll
        for (int i = 0; i < 4; i++) w4[i] = wr[i * 64 + lane];
        float acc[4] = {0.f, 0.f, 0.f, 0.f};
        #pragma unroll
        for (int bb = 0; bb < 4; ++bb) {
            const float4* zr = (const float4*)(ws + OFF_Z + (size_t)(bg7 * 4 + bb) * 1024);
            #pragma unroll
            for (int i = 0; i < 4; i++) {
                float4 z4 = zr[i * 64 + lane];
                acc[bb] += w4[i].x * z4.x + w4[i].y * z4.y + w4[i].z * z4.z + w4[i].w * z4.w;
            }
        }
        #pragma unroll
        for (int off = 32; off > 0; off >>= 1) {
            acc[0] += __shfl_xor(acc[0], off, 64);
            acc[1] += __shfl_xor(acc[1], off, 64);
            acc[2] += __shfl_xor(acc[2], off, 64);
            acc[3] += __shfl_xor(acc[3], off, 64);
        }
        if (lane == 0) {
            #pragma unroll
            for (int bb = 0; bb < 4; ++bb)
                ws[OFF_PP + ((size_t)((bg7 * 4 + bb) * 512 + a)) * 12 + 11] = acc[bb];
        }
    } else if (blockIdx.x < 1344) {
        int blk = blockIdx.x - 1024;   // 0..319
        int b = blk / 10, c = blk - b * 10;
        if (tid >= 250) return;
        float invS = __builtin_amdgcn_rcpf(ws[OFF_S + ((step + 1) & 1) * 32 + b]);
        int t = tid * 4;
        const float* ar = ws + OFF_AW + b * 1000;
        const float* wc = wconv + c * 201;
        float a0, a1, a2, a3;
        a0 = (t - 100 >= 0) ? ar[t - 100] : 0.f;
        a1 = (t -  99 >= 0) ? ar[t -  99] : 0.f;
        a2 = (t -  98 >= 0) ? ar[t -  98] : 0.f;
        a3 = (t -  97 >= 0) ? ar[t -  97] : 0.f;
        float c0 = 0.f, c1 = 0.f, c2 = 0.f, c3 = 0.f;
        #pragma unroll 4
        for (int j = 0; j < 201; ++j) {
            float w = wc[j];
            c0 += a0 * w; c1 += a1 * w; c2 += a2 * w; c3 += a3 * w;
            a0 = a1; a1 = a2; a2 = a3;
            int ni = t + j - 96;
            a3 = (ni >= 0 && ni < 1000) ? ar[ni] : 0.f;
        }
        float* o = ws + OFF_CONV + (size_t)(b * 10 + c) * 1000 + t;
        o[0] = c0 * invS; o[1] = c1 * invS; o[2] = c2 * invS; o[3] = c3 * invS;
    } else {
        __shared__ float wlds[32][132];
        __shared__ float xs[32][36];
        int blk = blockIdx.x - 1344;       // 0..255
        int nt = blk & 31, ks = blk >> 5;  // 32 ntiles x 8 ksplits
        int n0 = nt * 128;
        bool isE = (ks < 4);
        int kloc = isE ? ks * 256 : (ks - 4) * 256;
        int r = tid >> 1, h = tid & 1;
        int bx = tid >> 3, q8 = tid & 7;
        int tok = (step == 0) ? SOS_ : ys[bx * 100 + step - 1];
        const float* xsrc = isE ? (embed + (size_t)tok * 1024 + kloc)
                                : (ws + OFF_Z + (size_t)bx * 1024 + kloc);
        int nq = tid & 31, bq = tid >> 5;
        float acc[4][4] = {};
        for (int kc = 0; kc < 8; ++kc) {
            int koff = kc * 32;
            {
                const float* wrow = isE ? (wih + (size_t)(n0 + r) * 1536 + kloc + koff + h * 16)
                                        : (whh + (size_t)(n0 + r) * 1024 + kloc + koff + h * 16);
                #pragma unroll
                for (int j = 0; j < 4; ++j) {
                    float4 v = *(const float4*)&wrow[j * 4];
                    int kb = h * 16 + j * 4;
                    wlds[kb + 0][r] = v.x; wlds[kb + 1][r] = v.y;
                    wlds[kb + 2][r] = v.z; wlds[kb + 3][r] = v.w;
                }
            }
            {
                float4 v = *(const float4*)&xsrc[koff + q8 * 4];
                xs[q8 * 4 + 0][bx] = v.x; xs[q8 * 4 + 1][bx] = v.y;
                xs[q8 * 4 + 2][bx] = v.z; xs[q8 * 4 + 3][bx] = v.w;
            }
            __syncthreads();
            #pragma unroll 8
            for (int kk = 0; kk < 32; ++kk) {
                float4 wv = *(const float4*)&wlds[kk][nq * 4];
                float4 xv = *(const float4*)&xs[kk][bq * 4];
                float wa[4] = {wv.x, wv.y, wv.z, wv.w};
                float xa[4] = {xv.x, xv.y, xv.z, xv.w};
                #pragma unroll
                for (int i = 0; i < 4; i++)
                    #pragma unroll
                    for (int j = 0; j < 4; j++) acc[i][j] += wa[i] * xa[j];
            }
            __syncthreads();
        }
        float* gp = ws + OFF_GP + (size_t)(ks * 32 + bq * 4) * 4096 + n0 + nq * 4;
        #pragma unroll
        for (int j = 0; j < 4; j++)
            #pragma unroll
            for (int i = 0; i < 4; i++)
                gp[(size_t)j * 4096 + i] = acc[i][j];
    }
}

// ---------------- K2: fused energy + w~=exp(2e) + S + ctx ----------------
// 256 blocks x 512 threads. Block = (b, tchunk of 128 t). Wave w covers a in [w*64, w*64+64).
// Per-a params via UNIFORM (readfirstlane) pointer -> scalar s_load into SGPRs (no LDS/VMEM).
__global__ __launch_bounds__(512, 2) void k_ectx(const float* __restrict__ bgv,
                                                 float* ws, int step) {
    __shared__ float part[1024];
    __shared__ float wsh[128];
    const unsigned short* preb = (const unsigned short*)(ws + OFF_PRE);
    const unsigned short* hpb  = (const unsigned short*)(ws + OFF_HPB);
    int b = blockIdx.x >> 3, tc = blockIdx.x & 7;
    int tbase = tc * 128;
    int tid = threadIdx.x;
    int w = tid >> 6, l = tid & 63;
    int wu = __builtin_amdgcn_readfirstlane(w);     // wave-uniform wave index -> SGPR
    int t = tbase + l * 2;
    bool valid = (t < 1000);
    float2 cvv[10];
    const float* convb = ws + OFF_CONV + b * 10000;
    #pragma unroll
    for (int c = 0; c < 10; ++c)
        cvv[c] = valid ? *(const float2*)&convb[c * 1000 + t] : make_float2(0.f, 0.f);
    const float* pb = ws + OFF_PP + ((size_t)(b * 512 + wu * 64)) * 12;   // uniform base
    const unsigned short* pt = preb + ((size_t)(b * 512 + wu * 64)) * 1000 + t;
    float ex = 0.f, ey = 0.f;
    #pragma unroll 8
    for (int i = 0; i < 64; ++i) {
        unsigned u = valid ? *(const unsigned*)pt : 0u;
        pt += 1000;
        float4 q0 = *(const float4*)(pb + i * 12);       // watt0..3  (s_load)
        float4 q1 = *(const float4*)(pb + i * 12 + 4);   // watt4..7
        float4 q2 = *(const float4*)(pb + i * 12 + 8);   // watt8,9, gvec, dec
        float px = bflo(u), py = bfhi(u);
        float sx = px + q2.w, sy = py + q2.w;
        sx += cvv[0].x * q0.x; sy += cvv[0].y * q0.x;
        sx += cvv[1].x * q0.y; sy += cvv[1].y * q0.y;
        sx += cvv[2].x * q0.z; sy += cvv[2].y * q0.z;
        sx += cvv[3].x * q0.w; sy += cvv[3].y * q0.w;
        sx += cvv[4].x * q1.x; sy += cvv[4].y * q1.x;
        sx += cvv[5].x * q1.y; sy += cvv[5].y * q1.y;
        sx += cvv[6].x * q1.z; sy += cvv[6].y * q1.z;
        sx += cvv[7].x * q1.w; sy += cvv[7].y * q1.w;
        sx += cvv[8].x * q2.x; sy += cvv[8].y * q2.x;
        sx += cvv[9].x * q2.y; sy += cvv[9].y * q2.y;
        ex += q2.z * fast_tanh(sx);
        ey += q2.z * fast_tanh(sy);
    }
    part[w * 128 + l * 2]     = ex;
    part[w * 128 + l * 2 + 1] = ey;
    __syncthreads();
    float wtil = 0.f;
    if (tid < 128) {
        int tt = tbase + tid;
        float e = 0.f;
        #pragma unroll
        for (int j = 0; j < 8; ++j) e += part[j * 128 + tid];
        if (tt < 1000) {
            wtil = __expf(2.f * (e + bgv[0]));   // |2(e+bg)| <= ~17: no max-sub needed
            ws[OFF_AW + b * 1000 + tt] = wtil;
        }
        wsh[tid] = wtil;
    }
    __syncthreads();
    // S: 2 wave shuffle-reduces
    if (tid < 128) {
        float ss = wtil;
        #pragma unroll
        for (int off = 32; off > 0; off >>= 1) ss += __shfl_xor(ss, off, 64);
        if ((tid & 63) == 0) part[tid >> 6] = ss;
    }
    __syncthreads();
    if (tid == 0) atomicAdd(&ws[OFF_S + (step & 1) * 32 + b], part[0] + part[1]);
    // ctx accumulate for this t-chunk (bf16 hpad)
    int e4 = tid & 127, th = tid >> 7;
    int lt0 = th * 32;
    int ltend = lt0 + 32;
    int tmax = 1000 - tbase; if (ltend > tmax) ltend = tmax;
    float4 acc = make_float4(0.f, 0.f, 0.f, 0.f);
    for (int lt = lt0; lt < ltend; ++lt) {
        float wv = wsh[lt];
        uint2 hu = *(const uint2*)&hpb[((size_t)(b * 1000 + tbase + lt)) * 512 + e4 * 4];
        acc.x += wv * bflo(hu.x); acc.y += wv * bfhi(hu.x);
        acc.z += wv * bflo(hu.y); acc.w += wv * bfhi(hu.y);
    }
    float* cx = ws + OFF_CTX + b * 512 + e4 * 4;
    atomicAdd(cx + 0, acc.x); atomicAdd(cx + 1, acc.y);
    atomicAdd(cx + 2, acc.z); atomicAdd(cx + 3, acc.w);
}

// ---------------- K3: ctx-gates GEMM (normalized on load) + combine + LSTM ----------------
// 256 blocks x 256 threads. Block owns 4 d's -> 16 gate rows, K = ctx 512.
__global__ __launch_bounds__(256, 2) void k_gl(const float* __restrict__ wih,
                                               const float* __restrict__ bih,
                                               const float* __restrict__ bhh,
                                               float* ws, int step) {
    __shared__ float wlds[32][20];
    __shared__ float xs[32][33];
    __shared__ float glb[16][33];
    __shared__ float sinv[32];
    int tid = threadIdx.x;
    int d0 = blockIdx.x * 4;
    if (tid < 32) sinv[tid] = __builtin_amdgcn_rcpf(ws[OFF_S + (step & 1) * 32 + tid]);
    __syncthreads();
    int r = tid >> 4, h = tid & 15;    // W staging: 16 rows x 16 threads (2 k each)
    int ng_r = (r >> 2) * 1024 + d0 + (r & 3);
    const float* wrow = wih + (size_t)ng_r * 1536 + 1024 + h * 2;
    int bx = tid >> 3, q8 = tid & 7;   // x staging: 32 b x 8 threads (4 k each)
    const float* xsrc = ws + OFF_CTX + (size_t)bx * 512 + q8 * 4;
    float xscale = sinv[bx];
    int nq = tid & 7, bq = tid >> 3;   // compute: 8 ngroups (2 rows) x 32 b
    float acc[2] = {0.f, 0.f};
    for (int kc = 0; kc < 16; ++kc) {
        int k0 = kc * 32;
        {
            float2 v = *(const float2*)&wrow[k0];
            wlds[h * 2 + 0][r] = v.x;
            wlds[h * 2 + 1][r] = v.y;
        }
        {
            float4 v = *(const float4*)&xsrc[k0];
            xs[q8 * 4 + 0][bx] = v.x * xscale; xs[q8 * 4 + 1][bx] = v.y * xscale;
            xs[q8 * 4 + 2][bx] = v.z * xscale; xs[q8 * 4 + 3][bx] = v.w * xscale;
        }
        __syncthreads();
        #pragma unroll 8
        for (int kk = 0; kk < 32; ++kk) {
            float w0 = wlds[kk][nq * 2], w1 = wlds[kk][nq * 2 + 1];
            float x  = xs[kk][bq];
            acc[0] += w0 * x;
            acc[1] += w1 * x;
        }
        __syncthreads();
    }
    #pragma unroll
    for (int i = 0; i < 2; ++i) {
        int nl = nq * 2 + i;                      // 0..15
        int ng = (nl >> 2) * 1024 + d0 + (nl & 3);
        float s = acc[i] + bih[ng] + bhh[ng];
        #pragma unroll
        for (int sl = 0; sl < 8; ++sl)
            s += ws[OFF_GP + (size_t)(sl * 32 + bq) * 4096 + ng];
        glb[nl][bq] = s;
    }
    __syncthreads();
    if (tid < 128) {
        int dl = tid >> 5, b = tid & 31;
        float gi = glb[dl][b];
        float gf = glb[4 + dl][b];
        float gg = glb[8 + dl][b];
        float go = glb[12 + dl][b];
        int id = b * 1024 + d0 + dl;
        float c_old = ws[OFF_C + id];
        float si = fast_sigmoid(gi);
        float sf = fast_sigmoid(gf);
        float so = fast_sigmoid(go);
        float cn = sf * c_old + si * fast_tanh(gg);
        float hh = so * fast_tanh(cn);
        ws[OFF_C + id] = cn;
        ws[OFF_Z + id] = hh;
        ws[OFF_ZALL + ((size_t)step * 32 + b) * 1024 + d0 + dl] = hh;
    }
}

// ---------------- final: out = zall @ w_out^T + b_out (128x128 tile, 8x8/thread) ----------------
__global__ __launch_bounds__(256) void k_out(const float* __restrict__ zall,
                                             const float* __restrict__ wo,
                                             const float* __restrict__ bo,
                                             float* __restrict__ out) {
    __shared__ float As[16][132];
    __shared__ float Bs[16][132];
    int m0 = blockIdx.y * 128, n0 = blockIdx.x * 128;
    int tid = threadIdx.x;
    int tx = tid & 15, ty = tid >> 4;
    float acc[8][8] = {};
    int ar = tid >> 1, ah = (tid & 1) * 8;
    for (int k0 = 0; k0 < 1024; k0 += 16) {
        {
            int gm = m0 + ar;
            float4 a0, a1;
            if (gm < 3232) {
                a0 = *(const float4*)&zall[(size_t)gm * 1024 + k0 + ah];
                a1 = *(const float4*)&zall[(size_t)gm * 1024 + k0 + ah + 4];
            } else { a0 = a1 = make_float4(0.f, 0.f, 0.f, 0.f); }
            As[ah + 0][ar] = a0.x; As[ah + 1][ar] = a0.y; As[ah + 2][ar] = a0.z; As[ah + 3][ar] = a0.w;
            As[ah + 4][ar] = a1.x; As[ah + 5][ar] = a1.y; As[ah + 6][ar] = a1.z; As[ah + 7][ar] = a1.w;
            int gn = n0 + ar;
            float4 b0, b1;
            if (gn < 5000) {
                b0 = *(const float4*)&wo[(size_t)gn * 1024 + k0 + ah];
                b1 = *(const float4*)&wo[(size_t)gn * 1024 + k0 + ah + 4];
            } else { b0 = b1 = make_float4(0.f, 0.f, 0.f, 0.f); }
            Bs[ah + 0][ar] = b0.x; Bs[ah + 1][ar] = b0.y; Bs[ah + 2][ar] = b0.z; Bs[ah + 3][ar] = b0.w;
            Bs[ah + 4][ar] = b1.x; Bs[ah + 5][ar] = b1.y; Bs[ah + 6][ar] = b1.z; Bs[ah + 7][ar] = b1.w;
        }
        __syncthreads();
        #pragma unroll
        for (int kk = 0; kk < 16; ++kk) {
            float4 a0v = *(const float4*)&As[kk][ty * 8];
            float4 a1v = *(const float4*)&As[kk][ty * 8 + 4];
            float4 b0v = *(const float4*)&Bs[kk][tx * 8];
            float4 b1v = *(const float4*)&Bs[kk][tx * 8 + 4];
            float am[8] = {a0v.x, a0v.y, a0v.z, a0v.w, a1v.x, a1v.y, a1v.z, a1v.w};
            float bn[8] = {b0v.x, b0v.y, b0v.z, b0v.w, b1v.x, b1v.y, b1v.z, b1v.w};
            #pragma unroll
            for (int i = 0; i < 8; i++)
                #pragma unroll
                for (int j = 0; j < 8; j++) acc[i][j] += am[i] * bn[j];
        }
        __syncthreads();
    }
    #pragma unroll
    for (int i = 0; i < 8; i++) {
        int m = m0 + ty * 8 + i;
        if (m >= 3232) continue;
        int b = m & 31, o = m >> 5;
        #pragma unroll
        for (int j = 0; j < 8; j++) {
            int v = n0 + tx * 8 + j;
            if (v < 5000)
                out[((size_t)b * 101 + o) * 5000 + v] = acc[i][j] + bo[v];
        }
    }
}

extern "C" void kernel_launch(void* const* d_in, const int* in_sizes, int n_in,
                              void* d_out, int out_size, void* d_ws, size_t ws_size,
                              hipStream_t stream) {
    const float* hpad   = (const float*)d_in[0];
    const int*   ys     = (const int*)d_in[1];
    const float* w_enc  = (const float*)d_in[2];
    const float* b_enc  = (const float*)d_in[3];
    const float* w_dec  = (const float*)d_in[4];
    const float* w_att  = (const float*)d_in[5];
    const float* w_conv = (const float*)d_in[6];
    const float* w_gvec = (const float*)d_in[7];
    const float* b_gvec = (const float*)d_in[8];
    const float* embed  = (const float*)d_in[9];
    const float* w_ih   = (const float*)d_in[10];
    const float* w_hh   = (const float*)d_in[11];
    const float* b_ih   = (const float*)d_in[12];
    const float* b_hh   = (const float*)d_in[13];
    const float* w_out  = (const float*)d_in[14];
    const float* b_out  = (const float*)d_in[15];
    float* ws  = (float*)d_ws;
    float* out = (float*)d_out;

    k_init<<<128, 256, 0, stream>>>(w_att, w_gvec, ws);
    k_hp16<<<4000, 256, 0, stream>>>(hpad, ws);
    k_pre_t<<<dim3(8, 512), 256, 0, stream>>>(hpad, w_enc, b_enc, ws);

    for (int step = 0; step < OLEN_; ++step) {
        k_prep<<<1600, 256, 0, stream>>>(w_dec, w_conv, w_ih, w_hh, embed, ys, ws, step);
        k_ectx<<<256, 512, 0, stream>>>(b_gvec, ws, step);
        k_gl<<<256, 256, 0, stream>>>(w_ih, b_ih, b_hh, ws, step);
    }

    k_out<<<dim3(40, 26), 256, 0, stream>>>(ws + OFF_ZALL, w_out, b_out, out);
}